// Round 14
// baseline (199.790 us; speedup 1.0000x reference)
//
#include <hip/hip_runtime.h>
#include <hip/hip_fp16.h>

typedef _Float16 f16;
typedef _Float16 half4 __attribute__((ext_vector_type(4)));
typedef _Float16 half8 __attribute__((ext_vector_type(8)));
typedef float f32x4 __attribute__((ext_vector_type(4)));

#define BATCH 16
#define L 1024
#define H 1024

// ---- prep: W cvt (blocks [0,512)) | x cvt ([512,8704)) | mask scan ----
__global__ __launch_bounds__(256) void prep(const float* __restrict__ W,
                                            f16* __restrict__ Wh,
                                            const float* __restrict__ x,
                                            f16* __restrict__ Xh,
                                            const int* __restrict__ mask,
                                            int* __restrict__ posx,
                                            int* __restrict__ cntA) {
  __shared__ int wsum[4];
  const int t = threadIdx.x;
  if (blockIdx.x < 8704) {
    const float* src;
    f16* dst;
    long i;
    if (blockIdx.x < 512) {
      src = W; dst = Wh;
      i = (long)blockIdx.x * 2048 + t * 8;
    } else {
      src = x; dst = Xh;
      i = ((long)blockIdx.x - 512) * 2048 + t * 8;
    }
    const float4 a = *(const float4*)(&src[i]);
    const float4 b = *(const float4*)(&src[i + 4]);
    half8 h;
    h[0] = (f16)a.x; h[1] = (f16)a.y; h[2] = (f16)a.z; h[3] = (f16)a.w;
    h[4] = (f16)b.x; h[5] = (f16)b.y; h[6] = (f16)b.z; h[7] = (f16)b.w;
    *(half8*)(&dst[i]) = h;
    return;
  }
  // ---- mask scan for batch b ----
  const int b = blockIdx.x - 8704;
  const int4 mk = *(const int4*)(&mask[b * 1024 + t * 4]);
  const int f0 = (mk.x == 0), f1 = (mk.y == 0);
  const int f2 = (mk.z == 0), f3 = (mk.w == 0);
  const int s = f0 + f1 + f2 + f3;
  int v = s;
  const int lane = t & 63, wd = t >> 6;
  #pragma unroll
  for (int off = 1; off < 64; off <<= 1) {
    const int u = __shfl_up(v, off);
    if (lane >= off) v += u;
  }
  if (lane == 63) wsum[wd] = v;
  __syncthreads();
  int wb = 0;
  #pragma unroll
  for (int k = 0; k < 3; ++k)
    if (k < wd) wb += wsum[k];
  int e = wb + v - s;
  const int base = b * 1024 + t * 4;
  posx[base + 0] = e; e += f0;
  posx[base + 1] = e; e += f1;
  posx[base + 2] = e; e += f2;
  posx[base + 3] = e; e += f3;
  if (t == 255) cntA[b] = e;
}

// -- y [b,m,h] f32 -> Yhc (compact fp16 rows) + Ytc (compact transposed) --
__global__ __launch_bounds__(256) void transpose_y(
    const float* __restrict__ Y, const int* __restrict__ mask,
    const int* __restrict__ posx, const int* __restrict__ cntA,
    f16* __restrict__ Yhc, f16* __restrict__ Ytc) {
  __shared__ f16 tile[64][36];
  __shared__ int cmap[32];
  const int b = blockIdx.z;
  const int h0 = blockIdx.x * 64, m0 = blockIdx.y * 32;
  const int tid = threadIdx.x;
  const float* Yb = Y + (long)b * L * H;
  f16* Ytb = Ytc + (long)b * L * H;

  int rowbase = 0;
  #pragma unroll
  for (int k = 0; k < 16; ++k)
    if (k < b) rowbase += cntA[k];
  const int jbase = posx[b * 1024 + m0];
  const int cnt = cntA[b];
  const int nloc = ((m0 == L - 32) ? cnt : posx[b * 1024 + m0 + 32]) - jbase;

  const int hc = (tid & 15) * 4;
  #pragma unroll
  for (int rr = 0; rr < 2; ++rr) {
    const int m = (tid >> 4) + rr * 16;
    const int gm = b * 1024 + m0 + m;
    const int jc = posx[gm];
    const int un = (mask[gm] == 0);
    const float4 v = *(const float4*)(&Yb[(long)(m0 + m) * H + h0 + hc]);
    half4 h4;
    h4[0] = (f16)v.x; h4[1] = (f16)v.y; h4[2] = (f16)v.z; h4[3] = (f16)v.w;
    tile[hc + 0][m] = h4[0];
    tile[hc + 1][m] = h4[1];
    tile[hc + 2][m] = h4[2];
    tile[hc + 3][m] = h4[3];
    if (un) {
      *(half4*)(&Yhc[(long)(rowbase + jc) * H + h0 + hc]) = h4;
      if (hc == 0) cmap[jc - jbase] = m;
    }
  }
  __syncthreads();
  {
    const int c = tid & 31;
    if (c < nloc) {
      const int m = cmap[c];
      for (int hh = tid >> 5; hh < 64; hh += 8)
        Ytb[(long)(h0 + hh) * L + jbase + c] = tile[hh][m];
    }
  }
  if (m0 == L - 32) {
    const int p = ((cnt + 31) & ~31) - cnt;
    const int c = tid & 31;
    if (c < p)
      for (int hh = tid >> 5; hh < 64; hh += 8)
        Ytb[(long)(h0 + hh) * L + cnt + c] = (f16)0.f;
  }
}

#define GLD16(g, l)                                           \
  __builtin_amdgcn_global_load_lds(                           \
      (const __attribute__((address_space(1))) void*)(g),     \
      (__attribute__((address_space(3))) void*)(l), 16, 0, 0)

// ---- shared GEMM pipeline body (R5-proven, BK=32, NT steps) ----
#define GEMM_PIPELINE(NTv)                                                   \
  f32x4 acc[4][4];                                                           \
  _Pragma("unroll") for (int i = 0; i < 4; ++i)                              \
      _Pragma("unroll") for (int j = 0; j < 4; ++j)                          \
          acc[i][j] = (f32x4){0.f, 0.f, 0.f, 0.f};                           \
  _Pragma("unroll") for (int p = 0; p < 2; ++p) {                            \
    char* sb = ldsw + p * 24576;                                             \
    GLD16(gA0, sb + wid * 2048);                                             \
    GLD16(gA1, sb + wid * 2048 + 1024);                                      \
    GLD16(gB0, sb + 16384 + wid * 1024);                                     \
    gA0 += 32; gA1 += 32; gB0 += 32;                                         \
  }                                                                          \
  asm volatile("s_waitcnt vmcnt(3)" ::: "memory");                           \
  __builtin_amdgcn_s_barrier();                                              \
  __builtin_amdgcn_sched_barrier(0);                                         \
  int cb = 0, pb = 2 * 24576;                                                \
  for (int t = 0; t < NTv; ++t) {                                            \
    if (t + 2 < NTv) {                                                       \
      char* sb = ldsw + pb;                                                  \
      GLD16(gA0, sb + wid * 2048);                                           \
      GLD16(gA1, sb + wid * 2048 + 1024);                                    \
      GLD16(gB0, sb + 16384 + wid * 1024);                                   \
      gA0 += 32; gA1 += 32; gB0 += 32;                                       \
    }                                                                        \
    const char* base = ldsr + cb;                                            \
    half8 av[4], bv[4];                                                      \
    _Pragma("unroll") for (int j = 0; j < 4; ++j)                            \
        bv[j] = *(const half8*)(base + 16384 + bByte + j * 1024);            \
    _Pragma("unroll") for (int i = 0; i < 4; ++i)                            \
        av[i] = *(const half8*)(base + aByte + i * 1024);                    \
    __builtin_amdgcn_s_setprio(1);                                           \
    _Pragma("unroll") for (int i = 0; i < 4; ++i)                            \
        _Pragma("unroll") for (int j = 0; j < 4; ++j)                        \
            acc[i][j] = __builtin_amdgcn_mfma_f32_16x16x32_f16(              \
                av[i], bv[j], acc[i][j], 0, 0, 0);                           \
    __builtin_amdgcn_s_setprio(0);                                           \
    if (t < NTv - 1) {                                                       \
      __builtin_amdgcn_sched_barrier(0);                                     \
      if (t <= NTv - 3)                                                      \
        asm volatile("s_waitcnt vmcnt(3)" ::: "memory");                     \
      else                                                                   \
        asm volatile("s_waitcnt vmcnt(0)" ::: "memory");                     \
      __builtin_amdgcn_s_barrier();                                          \
      __builtin_amdgcn_sched_barrier(0);                                     \
      cb = (cb == 49152) ? 0 : cb + 24576;                                   \
      pb = (pb == 49152) ? 0 : pb + 24576;                                   \
    }                                                                        \
  }

// ===== proj (R13-proven, unchanged): mixed-tile XCD-affine =====
__global__ __launch_bounds__(512, 4) void gemm_proj(
    const f16* __restrict__ Ap, const f16* __restrict__ Wp,
    const float* __restrict__ bias, f16* __restrict__ Cp,
    const int* __restrict__ cntA) {
  __shared__ f16 lds[3 * 12288];
  constexpr int N = 1024, K = 1024;
  const int tid = threadIdx.x;
  const int lane = tid & 63;
  const int wid = tid >> 6;

  int total = 0;
  #pragma unroll
  for (int k = 0; k < 16; ++k) total += cntA[k];
  const int Mh = (total + 127) >> 7;

  const int x = blockIdx.x & 7;
  const int v = blockIdx.x >> 3;
  const int Hx = (Mh > x) ? 8 * ((Mh - x + 7) >> 3) : 0;
  bool full;
  int k;
  if (v < 128) {
    full = !(v & 1);
    k = v >> 1;
  } else {
    full = false;
    k = v - 64;
  }
  if (!full && k >= Hx) return;

  const int srow = lane >> 2;
  const int sslot = (lane & 3) ^ ((lane >> 3) & 3);
  const int fr = lane & 15, fq = lane >> 4;
  const int rsw = (fq ^ ((fr >> 1) & 3)) << 4;
  char* ldsw = (char*)lds;
  const char* ldsr = (const char*)lds;

  if (full) {
    const int q = x + 8 * (k >> 3);
    const int row0 = q * 256, col0 = (k & 7) * 128;
    const int wm = wid >> 1, wn = wid & 1;
    const int aByte = (wm * 64 + fr) * 64 + rsw;
    const int bByte = (wn * 64 + fr) * 64 + rsw;
    const f16* gA0 = Ap + (long)(row0 + wid * 32 + srow) * K + sslot * 8;
    const f16* gA1 = gA0 + 16L * K;
    const f16* gB0 = Wp + (long)(col0 + wid * 16 + srow) * K + sslot * 8;

    GEMM_PIPELINE(32)

    #pragma unroll
    for (int j = 0; j < 4; ++j) {
      const int col = col0 + wn * 64 + j * 16 + fr;
      const float bvs = bias[col];
      #pragma unroll
      for (int i = 0; i < 4; ++i) {
        const int rowb = row0 + wm * 64 + i * 16 + fq * 4;
        #pragma unroll
        for (int r = 0; r < 4; ++r) {
          float vv = acc[i][j][r] + bvs;
          vv = vv > 0.f ? vv : 0.f;
          Cp[(long)(rowb + r) * N + col] = (f16)vv;
        }
      }
    }
  } else {
    const int p = x + 8 * (k >> 3);
    const int row0 = 16384 + p * 128, col0 = (k & 7) * 128;
    const int wm2 = wid >> 2, wn2 = wid & 3;
    const int aByte = (wm2 * 64 + fr) * 64 + rsw;
    const int bByte = (wn2 * 32 + fr) * 64 + rsw;
    const f16* gA0 = Ap + (long)(row0 + wid * 16 + srow) * K + sslot * 8;
    const f16* gB0 = Wp + (long)(col0 + wid * 16 + srow) * K + sslot * 8;

    f32x4 acc[4][2];
    #pragma unroll
    for (int i = 0; i < 4; ++i)
      #pragma unroll
      for (int j = 0; j < 2; ++j)
        acc[i][j] = (f32x4){0.f, 0.f, 0.f, 0.f};
    #pragma unroll
    for (int p2 = 0; p2 < 2; ++p2) {
      char* sb = ldsw + p2 * 24576;
      GLD16(gA0, sb + wid * 1024);
      GLD16(gB0, sb + 16384 + wid * 1024);
      gA0 += 32; gB0 += 32;
    }
    asm volatile("s_waitcnt vmcnt(2)" ::: "memory");
    __builtin_amdgcn_s_barrier();
    __builtin_amdgcn_sched_barrier(0);
    int cb = 0, pb = 2 * 24576;
    for (int t = 0; t < 32; ++t) {
      if (t + 2 < 32) {
        char* sb = ldsw + pb;
        GLD16(gA0, sb + wid * 1024);
        GLD16(gB0, sb + 16384 + wid * 1024);
        gA0 += 32; gB0 += 32;
      }
      const char* base = ldsr + cb;
      half8 av[4], bv[2];
      #pragma unroll
      for (int j = 0; j < 2; ++j)
        bv[j] = *(const half8*)(base + 16384 + bByte + j * 1024);
      #pragma unroll
      for (int i = 0; i < 4; ++i)
        av[i] = *(const half8*)(base + aByte + i * 1024);
      __builtin_amdgcn_s_setprio(1);
      #pragma unroll
      for (int i = 0; i < 4; ++i)
        #pragma unroll
        for (int j = 0; j < 2; ++j)
          acc[i][j] = __builtin_amdgcn_mfma_f32_16x16x32_f16(av[i], bv[j],
                                                             acc[i][j], 0, 0, 0);
      __builtin_amdgcn_s_setprio(0);
      if (t < 31) {
        __builtin_amdgcn_sched_barrier(0);
        if (t <= 29)
          asm volatile("s_waitcnt vmcnt(2)" ::: "memory");
        else
          asm volatile("s_waitcnt vmcnt(0)" ::: "memory");
        __builtin_amdgcn_s_barrier();
        __builtin_amdgcn_sched_barrier(0);
        cb = (cb == 49152) ? 0 : cb + 24576;
        pb = (pb == 49152) ? 0 : pb + 24576;
      }
    }
    #pragma unroll
    for (int j = 0; j < 2; ++j) {
      const int col = col0 + wn2 * 32 + j * 16 + fr;
      const float bvs = bias[col];
      #pragma unroll
      for (int i = 0; i < 4; ++i) {
        const int rowb = row0 + wm2 * 64 + i * 16 + fq * 4;
        #pragma unroll
        for (int r = 0; r < 4; ++r) {
          float vv = acc[i][j][r] + bvs;
          vv = vv > 0.f ? vv : 0.f;
          Cp[(long)(rowb + r) * N + col] = (f16)vv;
        }
      }
    }
  }
}

// ===== scores: 128x128 tile, 4 waves, 3-slot LDS (48KB) -> 3 blocks/CU.
// Sc[b][l,j] = Xp[l,:] . Ypc[j,:], f32; col-exit at cnt32.
// Per step: 4 gloads (2A+2B chunks), 8 ds_read, 16 MFMA, vmcnt(4). =====
__global__ __launch_bounds__(256, 3) void gemm_scores(
    const f16* __restrict__ Ap, float* __restrict__ Cp,
    const int* __restrict__ cntA) {
  __shared__ f16 lds[3 * 8192];  // 3 slots x (A 8KB + B 8KB) = 48 KB
  constexpr int N = 1024, K = 1024, NT = 32;
  const int tid = threadIdx.x;
  const int lane = tid & 63;
  const int wid = tid >> 6;        // 0..3
  const int wm = wid >> 1, wn = wid & 1;

  const int nwg = gridDim.x;       // 1024
  const int orig = blockIdx.x;
  const int wg = (orig & 7) * (nwg >> 3) + (orig >> 3);
  const int bz = wg >> 6;          // 64 tiles/batch
  const int rxy = wg & 63;
  const int bx = rxy & 7;
  const int by = rxy >> 3;
  const int row0 = by * 128, col0 = bx * 128;

  int off = 0;
  #pragma unroll
  for (int k = 0; k < 16; ++k)
    if (k < bz) off += cntA[k];
  const int cnt = cntA[bz];
  const int cnt32 = (cnt + 31) & ~31;
  if (col0 >= cnt32) return;

  const int srow = lane >> 2;
  const int sslot = (lane & 3) ^ ((lane >> 3) & 3);
  const f16* gA0 = Ap + (long)(bz * 1024 + row0 + wid * 32 + srow) * K +
                   sslot * 8;
  const f16* gA1 = gA0 + 16L * K;
  const f16* gB0 = Ap + (long)(16384 + off + col0 + wid * 32 + srow) * K +
                   sslot * 8;
  const f16* gB1 = gB0 + 16L * K;
  char* ldsw = (char*)lds;
  const char* ldsr = (const char*)lds;

  const int fr = lane & 15, fq = lane >> 4;
  const int rsw = (fq ^ ((fr >> 1) & 3)) << 4;
  const int aByte = (wm * 64 + fr) * 64 + rsw;
  const int bByte = 8192 + (wn * 64 + fr) * 64 + rsw;

  f32x4 acc[4][4];
  #pragma unroll
  for (int i = 0; i < 4; ++i)
    #pragma unroll
    for (int j = 0; j < 4; ++j)
      acc[i][j] = (f32x4){0.f, 0.f, 0.f, 0.f};

  #pragma unroll
  for (int p = 0; p < 2; ++p) {
    char* sb = ldsw + p * 16384;
    GLD16(gA0, sb + wid * 2048);
    GLD16(gA1, sb + wid * 2048 + 1024);
    GLD16(gB0, sb + 8192 + wid * 2048);
    GLD16(gB1, sb + 8192 + wid * 2048 + 1024);
    gA0 += 32; gA1 += 32; gB0 += 32; gB1 += 32;
  }
  asm volatile("s_waitcnt vmcnt(4)" ::: "memory");
  __builtin_amdgcn_s_barrier();
  __builtin_amdgcn_sched_barrier(0);

  int cb = 0, pb = 2 * 16384;
  for (int t = 0; t < NT; ++t) {
    if (t + 2 < NT) {
      char* sb = ldsw + pb;
      GLD16(gA0, sb + wid * 2048);
      GLD16(gA1, sb + wid * 2048 + 1024);
      GLD16(gB0, sb + 8192 + wid * 2048);
      GLD16(gB1, sb + 8192 + wid * 2048 + 1024);
      gA0 += 32; gA1 += 32; gB0 += 32; gB1 += 32;
    }
    const char* base = ldsr + cb;
    half8 av[4], bv[4];
    #pragma unroll
    for (int j = 0; j < 4; ++j)
      bv[j] = *(const half8*)(base + bByte + j * 1024);
    #pragma unroll
    for (int i = 0; i < 4; ++i)
      av[i] = *(const half8*)(base + aByte + i * 1024);
    __builtin_amdgcn_s_setprio(1);
    #pragma unroll
    for (int i = 0; i < 4; ++i)
      #pragma unroll
      for (int j = 0; j < 4; ++j)
        acc[i][j] = __builtin_amdgcn_mfma_f32_16x16x32_f16(av[i], bv[j],
                                                           acc[i][j], 0, 0, 0);
    __builtin_amdgcn_s_setprio(0);
    if (t < NT - 1) {
      __builtin_amdgcn_sched_barrier(0);
      if (t <= NT - 3)
        asm volatile("s_waitcnt vmcnt(4)" ::: "memory");
      else
        asm volatile("s_waitcnt vmcnt(0)" ::: "memory");
      __builtin_amdgcn_s_barrier();
      __builtin_amdgcn_sched_barrier(0);
      cb = (cb == 32768) ? 0 : cb + 16384;
      pb = (pb == 32768) ? 0 : pb + 16384;
    }
  }

  float* C = Cp + (long)bz * (1 << 20);
  #pragma unroll
  for (int j = 0; j < 4; ++j) {
    const int col = col0 + wn * 64 + j * 16 + fr;
    #pragma unroll
    for (int i = 0; i < 4; ++i) {
      const int rowb = row0 + wm * 64 + i * 16 + fq * 4;
      #pragma unroll
      for (int r = 0; r < 4; ++r)
        C[(long)(rowb + r) * N + col] = acc[i][j][r];
    }
  }
}

// ---- PV: out[b][l,h] = Alpha[l,:cnt32] @ Ytc[h,:cnt32]^T, f32 ----
__global__ __launch_bounds__(512, 4) void gemm_pv(
    const f16* __restrict__ Ap, const f16* __restrict__ Bp,
    void* __restrict__ Cp, const int* __restrict__ cntA) {
  __shared__ f16 lds[3 * 12288];
  constexpr int N = 1024;
  const int tid = threadIdx.x;
  const int lane = tid & 63;
  const int wid = tid >> 6;
  const int wm = wid >> 1, wn = wid & 1;

  const int nwg = gridDim.x;
  const int orig = blockIdx.x;
  const int wg = (orig & 7) * (nwg >> 3) + (orig >> 3);
  const int bz = wg >> 5;
  const int rxy = wg & 31;
  const int bx = rxy & 7;
  const int by = rxy >> 3;
  const int row0 = by * 256, col0 = bx * 128;

  const int cnt = cntA[bz];
  const int cnt32 = (cnt + 31) & ~31;
  const int nt = cnt32 >> 5;

  const int srow = lane >> 2;
  const int sslot = (lane & 3) ^ ((lane >> 3) & 3);

  const f16* gA0 = Ap + (long)bz * (1 << 20) +
                   (long)(row0 + wid * 32 + srow) * 1024 + sslot * 8;
  const f16* gA1 = gA0 + 16L * 1024;
  const f16* gB0 = Bp + (long)bz * (1 << 20) +
                   (long)(col0 + wid * 16 + srow) * 1024 + sslot * 8;
  char* ldsw = (char*)lds;

  const int fr = lane & 15, fq = lane >> 4;
  const int rsw = (fq ^ ((fr >> 1) & 3)) << 4;
  const int aByte = (wm * 64 + fr) * 64 + rsw;
  const int bByte = (wn * 64 + fr) * 64 + rsw;
  const char* ldsr = (const char*)lds;

  const int NT = nt;
  GEMM_PIPELINE(NT)

  float* C = (float*)Cp + (long)bz * (1 << 20);
  #pragma unroll
  for (int j = 0; j < 4; ++j) {
    const int col = col0 + wn * 64 + j * 16 + fr;
    #pragma unroll
    for (int i = 0; i < 4; ++i) {
      const int rowb = row0 + wm * 64 + i * 16 + fq * 4;
      #pragma unroll
      for (int r = 0; r < 4; ++r)
        C[(long)(rowb + r) * N + col] = acc[i][j][r];
    }
  }
}

// ------- masked-compact row softmax: Sc f32 [b][l][j<cnt] -> alpha fp16 -------
__global__ __launch_bounds__(256) void softmax_rows(const float* __restrict__ S,
                                                    const int* __restrict__ cntA,
                                                    f16* __restrict__ P) {
  const int b = blockIdx.y;
  const int l = blockIdx.x;
  const int t = threadIdx.x;
  const int cnt = cntA[b];
  const int cnt32 = (cnt + 31) & ~31;
  const float* srow = S + ((long)b * L + l) * L;
  f16* prow = P + ((long)b * L + l) * L;

  const int j0 = t * 4;
  float4 v = make_float4(-1e30f, -1e30f, -1e30f, -1e30f);
  if (j0 < cnt32) v = *(const float4*)(&srow[j0]);
  const float x0 = (j0 + 0 < cnt) ? v.x : -1e30f;
  const float x1 = (j0 + 1 < cnt) ? v.y : -1e30f;
  const float x2 = (j0 + 2 < cnt) ? v.z : -1e30f;
  const float x3 = (j0 + 3 < cnt) ? v.w : -1e30f;

  float mx = fmaxf(fmaxf(x0, x1), fmaxf(x2, x3));
  #pragma unroll
  for (int off = 32; off >= 1; off >>= 1)
    mx = fmaxf(mx, __shfl_xor(mx, off));
  __shared__ float red[8];
  const int wd = t >> 6, lane = t & 63;
  if (lane == 0) red[wd] = mx;
  __syncthreads();
  mx = fmaxf(fmaxf(red[0], red[1]), fmaxf(red[2], red[3]));

  const float e0 = __expf(x0 - mx), e1 = __expf(x1 - mx);
  const float e2 = __expf(x2 - mx), e3 = __expf(x3 - mx);
  float s = e0 + e1 + e2 + e3;
  #pragma unroll
  for (int off = 32; off >= 1; off >>= 1)
    s += __shfl_xor(s, off);
  if (lane == 0) red[4 + wd] = s;
  __syncthreads();
  s = red[4] + red[5] + red[6] + red[7];
  const float inv = 1.f / s;
  if (j0 < cnt32) {
    half4 h;
    h[0] = (f16)(e0 * inv); h[1] = (f16)(e1 * inv);
    h[2] = (f16)(e2 * inv); h[3] = (f16)(e3 * inv);
    *(half4*)(&prow[j0]) = h;
  }
}

extern "C" void kernel_launch(void* const* d_in, const int* in_sizes, int n_in,
                              void* d_out, int out_size, void* d_ws,
                              size_t ws_size, hipStream_t stream) {
  const float* x = (const float*)d_in[0];
  const float* y = (const float*)d_in[1];
  const int* ymask = (const int*)d_in[2];
  const float* W = (const float*)d_in[3];
  const float* bias = (const float*)d_in[4];
  float* out = (float*)d_out;

  // ws: Wh 2MB | Ytc 32MB | XYp 64MB (meta in tail) | XYh 64MB (Sc alias)
  char* ws = (char*)d_ws;
  f16* Wh = (f16*)(ws);
  f16* Ytc = (f16*)(ws + (1L << 21));
  f16* XYp = (f16*)(ws + (1L << 21) + (1L << 25));
  f16* XYh = (f16*)(ws + (1L << 21) + (1L << 25) + (1L << 26));
  float* Sc = (float*)XYh;  // XYh dead after proj
  f16* Alpha = XYp;         // Xp rows dead after scores

  // meta in XYp tail (rows >= 30720 never touched by proj/scores/alpha)
  char* meta = (char*)XYp + 60L * (1 << 20);
  int* posx = (int*)meta;                 // 64 KB
  int* cntA = (int*)(meta + (1 << 16));   // 64 B

  f16* Xh = XYh;
  f16* Yhc = XYh + (long)BATCH * L * H;  // compact y rows

  prep<<<8704 + 16, 256, 0, stream>>>(W, Wh, x, Xh, ymask, posx, cntA);
  transpose_y<<<dim3(16, 32, BATCH), 256, 0, stream>>>(y, ymask, posx, cntA,
                                                       Yhc, Ytc);

  // proj: XYp[r] = relu(XYh[r] @ Wh^T + b), mixed-tile XCD-affine
  gemm_proj<<<1536, 512, 0, stream>>>(XYh, Wh, bias, XYp, cntA);

  // scores: Sc[b][l][j] = Xp[l] . Ypc[j]  (128x128, 3 blocks/CU)
  gemm_scores<<<1024, 256, 0, stream>>>(XYp, Sc, cntA);

  // alpha = softmax over j<cnt
  softmax_rows<<<dim3(L, BATCH), 256, 0, stream>>>(Sc, cntA, Alpha);

  // out[b][l][h] = sum_j alpha[l][j] * Ytc[h][j]
  gemm_pv<<<512, 512, 0, stream>>>(Alpha, Ytc, out, cntA);
}

// Round 15
// 193.301 us; speedup vs baseline: 1.0336x; 1.0336x over previous
//
#include <hip/hip_runtime.h>
#include <hip/hip_fp16.h>

typedef _Float16 f16;
typedef _Float16 half4 __attribute__((ext_vector_type(4)));
typedef _Float16 half8 __attribute__((ext_vector_type(8)));
typedef float f32x4 __attribute__((ext_vector_type(4)));

#define BATCH 16
#define L 1024
#define H 1024

// ---- prep: W cvt (blocks [0,512)) | x cvt ([512,8704)) | mask scan ----
__global__ __launch_bounds__(256) void prep(const float* __restrict__ W,
                                            f16* __restrict__ Wh,
                                            const float* __restrict__ x,
                                            f16* __restrict__ Xh,
                                            const int* __restrict__ mask,
                                            int* __restrict__ posx,
                                            int* __restrict__ cntA) {
  __shared__ int wsum[4];
  const int t = threadIdx.x;
  if (blockIdx.x < 8704) {
    const float* src;
    f16* dst;
    long i;
    if (blockIdx.x < 512) {
      src = W; dst = Wh;
      i = (long)blockIdx.x * 2048 + t * 8;
    } else {
      src = x; dst = Xh;
      i = ((long)blockIdx.x - 512) * 2048 + t * 8;
    }
    const float4 a = *(const float4*)(&src[i]);
    const float4 b = *(const float4*)(&src[i + 4]);
    half8 h;
    h[0] = (f16)a.x; h[1] = (f16)a.y; h[2] = (f16)a.z; h[3] = (f16)a.w;
    h[4] = (f16)b.x; h[5] = (f16)b.y; h[6] = (f16)b.z; h[7] = (f16)b.w;
    *(half8*)(&dst[i]) = h;
    return;
  }
  // ---- mask scan for batch b ----
  const int b = blockIdx.x - 8704;
  const int4 mk = *(const int4*)(&mask[b * 1024 + t * 4]);
  const int f0 = (mk.x == 0), f1 = (mk.y == 0);
  const int f2 = (mk.z == 0), f3 = (mk.w == 0);
  const int s = f0 + f1 + f2 + f3;
  int v = s;
  const int lane = t & 63, wd = t >> 6;
  #pragma unroll
  for (int off = 1; off < 64; off <<= 1) {
    const int u = __shfl_up(v, off);
    if (lane >= off) v += u;
  }
  if (lane == 63) wsum[wd] = v;
  __syncthreads();
  int wb = 0;
  #pragma unroll
  for (int k = 0; k < 3; ++k)
    if (k < wd) wb += wsum[k];
  int e = wb + v - s;
  const int base = b * 1024 + t * 4;
  posx[base + 0] = e; e += f0;
  posx[base + 1] = e; e += f1;
  posx[base + 2] = e; e += f2;
  posx[base + 3] = e; e += f3;
  if (t == 255) cntA[b] = e;
}

// -- y [b,m,h] f32 -> Yhc (compact fp16 rows) + Ytc (compact transposed) --
__global__ __launch_bounds__(256) void transpose_y(
    const float* __restrict__ Y, const int* __restrict__ mask,
    const int* __restrict__ posx, const int* __restrict__ cntA,
    f16* __restrict__ Yhc, f16* __restrict__ Ytc) {
  __shared__ f16 tile[64][36];
  __shared__ int cmap[32];
  const int b = blockIdx.z;
  const int h0 = blockIdx.x * 64, m0 = blockIdx.y * 32;
  const int tid = threadIdx.x;
  const float* Yb = Y + (long)b * L * H;
  f16* Ytb = Ytc + (long)b * L * H;

  int rowbase = 0;
  #pragma unroll
  for (int k = 0; k < 16; ++k)
    if (k < b) rowbase += cntA[k];
  const int jbase = posx[b * 1024 + m0];
  const int cnt = cntA[b];
  const int nloc = ((m0 == L - 32) ? cnt : posx[b * 1024 + m0 + 32]) - jbase;

  const int hc = (tid & 15) * 4;
  #pragma unroll
  for (int rr = 0; rr < 2; ++rr) {
    const int m = (tid >> 4) + rr * 16;
    const int gm = b * 1024 + m0 + m;
    const int jc = posx[gm];
    const int un = (mask[gm] == 0);
    const float4 v = *(const float4*)(&Yb[(long)(m0 + m) * H + h0 + hc]);
    half4 h4;
    h4[0] = (f16)v.x; h4[1] = (f16)v.y; h4[2] = (f16)v.z; h4[3] = (f16)v.w;
    tile[hc + 0][m] = h4[0];
    tile[hc + 1][m] = h4[1];
    tile[hc + 2][m] = h4[2];
    tile[hc + 3][m] = h4[3];
    if (un) {
      *(half4*)(&Yhc[(long)(rowbase + jc) * H + h0 + hc]) = h4;
      if (hc == 0) cmap[jc - jbase] = m;
    }
  }
  __syncthreads();
  {
    const int c = tid & 31;
    if (c < nloc) {
      const int m = cmap[c];
      for (int hh = tid >> 5; hh < 64; hh += 8)
        Ytb[(long)(h0 + hh) * L + jbase + c] = tile[hh][m];
    }
  }
  if (m0 == L - 32) {
    const int p = ((cnt + 31) & ~31) - cnt;
    const int c = tid & 31;
    if (c < p)
      for (int hh = tid >> 5; hh < 64; hh += 8)
        Ytb[(long)(h0 + hh) * L + cnt + c] = (f16)0.f;
  }
}

#define GLD16(g, l)                                           \
  __builtin_amdgcn_global_load_lds(                           \
      (const __attribute__((address_space(1))) void*)(g),     \
      (__attribute__((address_space(3))) void*)(l), 16, 0, 0)

// ---- shared GEMM pipeline body (R5-proven, BK=32, NT steps) ----
#define GEMM_PIPELINE(NTv)                                                   \
  f32x4 acc[4][4];                                                           \
  _Pragma("unroll") for (int i = 0; i < 4; ++i)                              \
      _Pragma("unroll") for (int j = 0; j < 4; ++j)                          \
          acc[i][j] = (f32x4){0.f, 0.f, 0.f, 0.f};                           \
  _Pragma("unroll") for (int p = 0; p < 2; ++p) {                            \
    char* sb = ldsw + p * 24576;                                             \
    GLD16(gA0, sb + wid * 2048);                                             \
    GLD16(gA1, sb + wid * 2048 + 1024);                                      \
    GLD16(gB0, sb + 16384 + wid * 1024);                                     \
    gA0 += 32; gA1 += 32; gB0 += 32;                                         \
  }                                                                          \
  asm volatile("s_waitcnt vmcnt(3)" ::: "memory");                           \
  __builtin_amdgcn_s_barrier();                                              \
  __builtin_amdgcn_sched_barrier(0);                                         \
  int cb = 0, pb = 2 * 24576;                                                \
  for (int t = 0; t < NTv; ++t) {                                            \
    if (t + 2 < NTv) {                                                       \
      char* sb = ldsw + pb;                                                  \
      GLD16(gA0, sb + wid * 2048);                                           \
      GLD16(gA1, sb + wid * 2048 + 1024);                                    \
      GLD16(gB0, sb + 16384 + wid * 1024);                                   \
      gA0 += 32; gA1 += 32; gB0 += 32;                                       \
    }                                                                        \
    const char* base = ldsr + cb;                                            \
    half8 av[4], bv[4];                                                      \
    _Pragma("unroll") for (int j = 0; j < 4; ++j)                            \
        bv[j] = *(const half8*)(base + 16384 + bByte + j * 1024);            \
    _Pragma("unroll") for (int i = 0; i < 4; ++i)                            \
        av[i] = *(const half8*)(base + aByte + i * 1024);                    \
    __builtin_amdgcn_s_setprio(1);                                           \
    _Pragma("unroll") for (int i = 0; i < 4; ++i)                            \
        _Pragma("unroll") for (int j = 0; j < 4; ++j)                        \
            acc[i][j] = __builtin_amdgcn_mfma_f32_16x16x32_f16(              \
                av[i], bv[j], acc[i][j], 0, 0, 0);                           \
    __builtin_amdgcn_s_setprio(0);                                           \
    if (t < NTv - 1) {                                                       \
      __builtin_amdgcn_sched_barrier(0);                                     \
      if (t <= NTv - 3)                                                      \
        asm volatile("s_waitcnt vmcnt(3)" ::: "memory");                     \
      else                                                                   \
        asm volatile("s_waitcnt vmcnt(0)" ::: "memory");                     \
      __builtin_amdgcn_s_barrier();                                          \
      __builtin_amdgcn_sched_barrier(0);                                     \
      cb = (cb == 49152) ? 0 : cb + 24576;                                   \
      pb = (pb == 49152) ? 0 : pb + 24576;                                   \
    }                                                                        \
  }

// ===== proj (R13-proven): mixed-tile XCD-affine =====
__global__ __launch_bounds__(512, 4) void gemm_proj(
    const f16* __restrict__ Ap, const f16* __restrict__ Wp,
    const float* __restrict__ bias, f16* __restrict__ Cp,
    const int* __restrict__ cntA) {
  __shared__ f16 lds[3 * 12288];
  constexpr int N = 1024, K = 1024;
  const int tid = threadIdx.x;
  const int lane = tid & 63;
  const int wid = tid >> 6;

  int total = 0;
  #pragma unroll
  for (int k = 0; k < 16; ++k) total += cntA[k];
  const int Mh = (total + 127) >> 7;

  const int x = blockIdx.x & 7;
  const int v = blockIdx.x >> 3;
  const int Hx = (Mh > x) ? 8 * ((Mh - x + 7) >> 3) : 0;
  bool full;
  int k;
  if (v < 128) {
    full = !(v & 1);
    k = v >> 1;
  } else {
    full = false;
    k = v - 64;
  }
  if (!full && k >= Hx) return;

  const int srow = lane >> 2;
  const int sslot = (lane & 3) ^ ((lane >> 3) & 3);
  const int fr = lane & 15, fq = lane >> 4;
  const int rsw = (fq ^ ((fr >> 1) & 3)) << 4;
  char* ldsw = (char*)lds;
  const char* ldsr = (const char*)lds;

  if (full) {
    const int q = x + 8 * (k >> 3);
    const int row0 = q * 256, col0 = (k & 7) * 128;
    const int wm = wid >> 1, wn = wid & 1;
    const int aByte = (wm * 64 + fr) * 64 + rsw;
    const int bByte = (wn * 64 + fr) * 64 + rsw;
    const f16* gA0 = Ap + (long)(row0 + wid * 32 + srow) * K + sslot * 8;
    const f16* gA1 = gA0 + 16L * K;
    const f16* gB0 = Wp + (long)(col0 + wid * 16 + srow) * K + sslot * 8;

    GEMM_PIPELINE(32)

    #pragma unroll
    for (int j = 0; j < 4; ++j) {
      const int col = col0 + wn * 64 + j * 16 + fr;
      const float bvs = bias[col];
      #pragma unroll
      for (int i = 0; i < 4; ++i) {
        const int rowb = row0 + wm * 64 + i * 16 + fq * 4;
        #pragma unroll
        for (int r = 0; r < 4; ++r) {
          float vv = acc[i][j][r] + bvs;
          vv = vv > 0.f ? vv : 0.f;
          Cp[(long)(rowb + r) * N + col] = (f16)vv;
        }
      }
    }
  } else {
    const int p = x + 8 * (k >> 3);
    const int row0 = 16384 + p * 128, col0 = (k & 7) * 128;
    const int wm2 = wid >> 2, wn2 = wid & 3;
    const int aByte = (wm2 * 64 + fr) * 64 + rsw;
    const int bByte = (wn2 * 32 + fr) * 64 + rsw;
    const f16* gA0 = Ap + (long)(row0 + wid * 16 + srow) * K + sslot * 8;
    const f16* gB0 = Wp + (long)(col0 + wid * 16 + srow) * K + sslot * 8;

    f32x4 acc[4][2];
    #pragma unroll
    for (int i = 0; i < 4; ++i)
      #pragma unroll
      for (int j = 0; j < 2; ++j)
        acc[i][j] = (f32x4){0.f, 0.f, 0.f, 0.f};
    #pragma unroll
    for (int p2 = 0; p2 < 2; ++p2) {
      char* sb = ldsw + p2 * 24576;
      GLD16(gA0, sb + wid * 1024);
      GLD16(gB0, sb + 16384 + wid * 1024);
      gA0 += 32; gB0 += 32;
    }
    asm volatile("s_waitcnt vmcnt(2)" ::: "memory");
    __builtin_amdgcn_s_barrier();
    __builtin_amdgcn_sched_barrier(0);
    int cb = 0, pb = 2 * 24576;
    for (int t = 0; t < 32; ++t) {
      if (t + 2 < 32) {
        char* sb = ldsw + pb;
        GLD16(gA0, sb + wid * 1024);
        GLD16(gB0, sb + 16384 + wid * 1024);
        gA0 += 32; gB0 += 32;
      }
      const char* base = ldsr + cb;
      half8 av[4], bv[2];
      #pragma unroll
      for (int j = 0; j < 2; ++j)
        bv[j] = *(const half8*)(base + 16384 + bByte + j * 1024);
      #pragma unroll
      for (int i = 0; i < 4; ++i)
        av[i] = *(const half8*)(base + aByte + i * 1024);
      __builtin_amdgcn_s_setprio(1);
      #pragma unroll
      for (int i = 0; i < 4; ++i)
        #pragma unroll
        for (int j = 0; j < 2; ++j)
          acc[i][j] = __builtin_amdgcn_mfma_f32_16x16x32_f16(av[i], bv[j],
                                                             acc[i][j], 0, 0, 0);
      __builtin_amdgcn_s_setprio(0);
      if (t < 31) {
        __builtin_amdgcn_sched_barrier(0);
        if (t <= 29)
          asm volatile("s_waitcnt vmcnt(2)" ::: "memory");
        else
          asm volatile("s_waitcnt vmcnt(0)" ::: "memory");
        __builtin_amdgcn_s_barrier();
        __builtin_amdgcn_sched_barrier(0);
        cb = (cb == 49152) ? 0 : cb + 24576;
        pb = (pb == 49152) ? 0 : pb + 24576;
      }
    }
    #pragma unroll
    for (int j = 0; j < 2; ++j) {
      const int col = col0 + wn2 * 32 + j * 16 + fr;
      const float bvs = bias[col];
      #pragma unroll
      for (int i = 0; i < 4; ++i) {
        const int rowb = row0 + wm2 * 64 + i * 16 + fq * 4;
        #pragma unroll
        for (int r = 0; r < 4; ++r) {
          float vv = acc[i][j][r] + bvs;
          vv = vv > 0.f ? vv : 0.f;
          Cp[(long)(rowb + r) * N + col] = (f16)vv;
        }
      }
    }
  }
}

// ---- MODE 1: scores Sc[b][l,j]=Xp@Ypc^T f32 (col-exit at cnt32)
// ---- MODE 2: PV     out[b][l,h]=Alpha@Ytc^T f32 (runtime NT=cnt32/32)
template <int MODE>
__global__ __launch_bounds__(512, 4) void gemm128(
    const f16* __restrict__ Ap, const f16* __restrict__ Bp,
    void* __restrict__ Cp, const int* __restrict__ cntA) {
  __shared__ f16 lds[3 * 12288];
  constexpr int N = 1024, K = 1024;
  const int tid = threadIdx.x;
  const int lane = tid & 63;
  const int wid = tid >> 6;
  const int wm = wid >> 1, wn = wid & 1;

  const int nwg = gridDim.x;
  const int orig = blockIdx.x;
  const int wg = (orig & 7) * (nwg >> 3) + (orig >> 3);
  const int bz = wg >> 5;
  const int rxy = wg & 31;
  const int bx = rxy & 7;
  const int by = rxy >> 3;
  const int row0 = by * 256, col0 = bx * 128;

  int off = 0;
  #pragma unroll
  for (int k = 0; k < 16; ++k)
    if (k < bz) off += cntA[k];
  const int cnt = cntA[bz];
  const int cnt32 = (cnt + 31) & ~31;

  const int srow = lane >> 2;
  const int sslot = (lane & 3) ^ ((lane >> 3) & 3);

  int nt = 32;
  const f16 *gA0, *gA1, *gB0;
  if (MODE == 1) {
    if (col0 >= cnt32) return;
    gA0 = Ap + (long)(bz * 1024 + row0 + wid * 32 + srow) * K + sslot * 8;
    gA1 = gA0 + 16L * K;
    gB0 = Ap + (long)(16384 + off + col0 + wid * 16 + srow) * K + sslot * 8;
  } else {
    nt = cnt32 >> 5;
    gA0 = Ap + (long)bz * (1 << 20) +
          (long)(row0 + wid * 32 + srow) * 1024 + sslot * 8;
    gA1 = gA0 + 16L * 1024;
    gB0 = Bp + (long)bz * (1 << 20) +
          (long)(col0 + wid * 16 + srow) * 1024 + sslot * 8;
  }
  char* ldsw = (char*)lds;

  const int fr = lane & 15, fq = lane >> 4;
  const int rsw = (fq ^ ((fr >> 1) & 3)) << 4;
  const int aByte = (wm * 64 + fr) * 64 + rsw;
  const int bByte = (wn * 64 + fr) * 64 + rsw;
  const char* ldsr = (const char*)lds;

  const int NT = (MODE == 2) ? nt : 32;
  GEMM_PIPELINE(NT)

  float* C = (float*)Cp + (long)bz * (1 << 20);
  #pragma unroll
  for (int j = 0; j < 4; ++j) {
    const int col = col0 + wn * 64 + j * 16 + fr;
    #pragma unroll
    for (int i = 0; i < 4; ++i) {
      const int rowb = row0 + wm * 64 + i * 16 + fq * 4;
      #pragma unroll
      for (int r = 0; r < 4; ++r)
        C[(long)(rowb + r) * N + col] = acc[i][j][r];
    }
  }
}

// ------- masked-compact row softmax: Sc f32 [b][l][j<cnt] -> alpha fp16 -------
__global__ __launch_bounds__(256) void softmax_rows(const float* __restrict__ S,
                                                    const int* __restrict__ cntA,
                                                    f16* __restrict__ P) {
  const int b = blockIdx.y;
  const int l = blockIdx.x;
  const int t = threadIdx.x;
  const int cnt = cntA[b];
  const int cnt32 = (cnt + 31) & ~31;
  const float* srow = S + ((long)b * L + l) * L;
  f16* prow = P + ((long)b * L + l) * L;

  const int j0 = t * 4;
  float4 v = make_float4(-1e30f, -1e30f, -1e30f, -1e30f);
  if (j0 < cnt32) v = *(const float4*)(&srow[j0]);
  const float x0 = (j0 + 0 < cnt) ? v.x : -1e30f;
  const float x1 = (j0 + 1 < cnt) ? v.y : -1e30f;
  const float x2 = (j0 + 2 < cnt) ? v.z : -1e30f;
  const float x3 = (j0 + 3 < cnt) ? v.w : -1e30f;

  float mx = fmaxf(fmaxf(x0, x1), fmaxf(x2, x3));
  #pragma unroll
  for (int off = 32; off >= 1; off >>= 1)
    mx = fmaxf(mx, __shfl_xor(mx, off));
  __shared__ float red[8];
  const int wd = t >> 6, lane = t & 63;
  if (lane == 0) red[wd] = mx;
  __syncthreads();
  mx = fmaxf(fmaxf(red[0], red[1]), fmaxf(red[2], red[3]));

  const float e0 = __expf(x0 - mx), e1 = __expf(x1 - mx);
  const float e2 = __expf(x2 - mx), e3 = __expf(x3 - mx);
  float s = e0 + e1 + e2 + e3;
  #pragma unroll
  for (int off = 32; off >= 1; off >>= 1)
    s += __shfl_xor(s, off);
  if (lane == 0) red[4 + wd] = s;
  __syncthreads();
  s = red[4] + red[5] + red[6] + red[7];
  const float inv = 1.f / s;
  if (j0 < cnt32) {
    half4 h;
    h[0] = (f16)(e0 * inv); h[1] = (f16)(e1 * inv);
    h[2] = (f16)(e2 * inv); h[3] = (f16)(e3 * inv);
    *(half4*)(&prow[j0]) = h;
  }
}

extern "C" void kernel_launch(void* const* d_in, const int* in_sizes, int n_in,
                              void* d_out, int out_size, void* d_ws,
                              size_t ws_size, hipStream_t stream) {
  const float* x = (const float*)d_in[0];
  const float* y = (const float*)d_in[1];
  const int* ymask = (const int*)d_in[2];
  const float* W = (const float*)d_in[3];
  const float* bias = (const float*)d_in[4];
  float* out = (float*)d_out;

  // ws: Wh 2MB | Ytc 32MB | XYp 64MB (meta in tail) | XYh 64MB (Sc alias)
  char* ws = (char*)d_ws;
  f16* Wh = (f16*)(ws);
  f16* Ytc = (f16*)(ws + (1L << 21));
  f16* XYp = (f16*)(ws + (1L << 21) + (1L << 25));
  f16* XYh = (f16*)(ws + (1L << 21) + (1L << 25) + (1L << 26));
  float* Sc = (float*)XYh;  // XYh dead after proj
  f16* Alpha = XYp;         // Xp rows dead after scores

  // meta in XYp tail (rows >= 30720 never touched by proj/scores/alpha)
  char* meta = (char*)XYp + 60L * (1 << 20);
  int* posx = (int*)meta;                 // 64 KB
  int* cntA = (int*)(meta + (1 << 16));   // 64 B

  f16* Xh = XYh;
  f16* Yhc = XYh + (long)BATCH * L * H;  // compact y rows

  prep<<<8704 + 16, 256, 0, stream>>>(W, Wh, x, Xh, ymask, posx, cntA);
  transpose_y<<<dim3(16, 32, BATCH), 256, 0, stream>>>(y, ymask, posx, cntA,
                                                       Yhc, Ytc);

  // proj: XYp[r] = relu(XYh[r] @ Wh^T + b), mixed-tile XCD-affine
  gemm_proj<<<1536, 512, 0, stream>>>(XYh, Wh, bias, XYp, cntA);

  // scores: Sc[b][l][j] = Xp[l] . Ypc[j]
  gemm128<1><<<512, 512, 0, stream>>>(XYp, nullptr, Sc, cntA);

  // alpha = softmax over j<cnt
  softmax_rows<<<dim3(L, BATCH), 256, 0, stream>>>(Sc, cntA, Alpha);

  // out[b][l][h] = sum_j alpha[l][j] * Ytc[h][j]
  gemm128<2><<<512, 512, 0, stream>>>(Alpha, Ytc, out, cntA);
}